// Round 1
// baseline (120.680 us; speedup 1.0000x reference)
//
#include <hip/hip_runtime.h>

#define TWO_LOG2E 2.8853900817779268f   // 2*log2(e)
#define LOG2E     1.4426950408889634f

// ---------------------------------------------------------------------------
// Kernel P: fused Q/K projection GEMM, epilogue E = exp(2*proj)
//   rows 0..1023   : q-proj (query @ Wq)  -> Eq[row][h]        (row-major)
//   rows 1024..5119: k-proj (key @ Wk)    -> EkT[b][h][k]      (transposed)
// grid (4 n-tiles, 80 m-tiles), 256 threads, 64x64 tile, K=512 in steps of 16
// ---------------------------------------------------------------------------
__global__ __launch_bounds__(256) void proj_kernel(
    const float* __restrict__ query, const float* __restrict__ key,
    const float* __restrict__ Wq, const float* __restrict__ Wk,
    float* __restrict__ Eq, float* __restrict__ EkT)
{
    __shared__ float lds[64 * 66];                 // 16.5 KiB, unioned
    float (*As)[68] = (float(*)[68])lds;           // [16][68]  (k-major, padded)
    float (*Bs)[64] = (float(*)[64])(lds + 16 * 68);

    const int tid = threadIdx.x;
    const int tx = tid & 15, ty = tid >> 4;
    const int m0 = blockIdx.y * 64, n0 = blockIdx.x * 64;
    const bool isq = (m0 < 1024);
    const float* Ap = isq ? (query + (size_t)m0 * 512)
                          : (key + (size_t)(m0 - 1024) * 512);
    const float* Bp = isq ? Wq : Wk;

    const int lr = tid >> 2, lc = (tid & 3) * 4;   // A-tile: 64 rows x 16 k
    const int br = tid >> 4, bc = (tid & 15) * 4;  // B-tile: 16 k x 64 n

    float c[4][4] = {};

    for (int kt = 0; kt < 512; kt += 16) {
        const float4 av = *(const float4*)(Ap + (size_t)lr * 512 + kt + lc);
        const float4 bv = *(const float4*)(Bp + (size_t)(kt + br) * 256 + n0 + bc);
        __syncthreads();
        As[lc + 0][lr] = av.x; As[lc + 1][lr] = av.y;
        As[lc + 2][lr] = av.z; As[lc + 3][lr] = av.w;
        *(float4*)&Bs[br][bc] = bv;
        __syncthreads();
        #pragma unroll
        for (int k = 0; k < 16; ++k) {
            const float4 a = *(const float4*)&As[k][ty * 4];
            const float4 bb = *(const float4*)&Bs[k][tx * 4];
            const float ar[4] = {a.x, a.y, a.z, a.w};
            const float brr[4] = {bb.x, bb.y, bb.z, bb.w};
            #pragma unroll
            for (int i = 0; i < 4; ++i)
                #pragma unroll
                for (int j = 0; j < 4; ++j)
                    c[i][j] = fmaf(ar[i], brr[j], c[i][j]);
        }
    }

    if (isq) {
        #pragma unroll
        for (int i = 0; i < 4; ++i) {
            float4 o;
            o.x = __builtin_amdgcn_exp2f(c[i][0] * TWO_LOG2E);
            o.y = __builtin_amdgcn_exp2f(c[i][1] * TWO_LOG2E);
            o.z = __builtin_amdgcn_exp2f(c[i][2] * TWO_LOG2E);
            o.w = __builtin_amdgcn_exp2f(c[i][3] * TWO_LOG2E);
            *(float4*)(Eq + (size_t)(m0 + ty * 4 + i) * 256 + n0 + tx * 4) = o;
        }
    } else {
        __syncthreads();                            // done with As/Bs
        float (*Ct)[66] = (float(*)[66])lds;        // [64 h][66] transposed tile
        #pragma unroll
        for (int i = 0; i < 4; ++i)
            #pragma unroll
            for (int j = 0; j < 4; ++j)
                Ct[tx * 4 + j][ty * 4 + i] =
                    __builtin_amdgcn_exp2f(c[i][j] * TWO_LOG2E);
        __syncthreads();
        const int krow0 = m0 - 1024;
        const int b = krow0 >> 10, kk0 = krow0 & 1023;
        const int hr = tid >> 2, mc = (tid & 3) * 4;
        #pragma unroll
        for (int rep = 0; rep < 4; ++rep) {
            const int m = mc + rep * 16;
            float4 o;
            o.x = Ct[hr][m]; o.y = Ct[hr][m + 1];
            o.z = Ct[hr][m + 2]; o.w = Ct[hr][m + 3];
            *(float4*)(EkT + (size_t)(b * 256 + n0 + hr) * 1024 + kk0 + m) = o;
        }
    }
}

// ---------------------------------------------------------------------------
// Kernel C: score + masked softmax.
// score[b,q,k] = sum_h wv[h]*tanh(qp+kp) = C1 - 2*sum_h wv[h]*rcp(Eq*Ek + 1)
// block = (b, 4 q-rows); 512 threads; thread owns k = 2*tid, 2*tid+1.
// ---------------------------------------------------------------------------
__global__ __launch_bounds__(512) void score_softmax_kernel(
    const float* __restrict__ Eq, const float* __restrict__ EkT,
    const float* __restrict__ wv, const int* __restrict__ valid_len,
    float* __restrict__ attn)
{
    __shared__ float wv_s[256];
    __shared__ float eq_s[1024];     // 4 q rows x 256 h
    __shared__ float red[8][4];

    const int tid = threadIdx.x;
    const int b = blockIdx.x >> 6;
    const int q0 = (blockIdx.x & 63) << 2;

    if (tid < 256) wv_s[tid] = wv[tid];
    *(float2*)&eq_s[tid * 2] =
        *(const float2*)(Eq + (size_t)(b * 256 + q0) * 256 + tid * 2);
    __syncthreads();

    float acc[4][2] = {};
    float cw = 0.f;
    const float* ekp = EkT + (size_t)(b * 256) * 1024 + tid * 2;

    #pragma unroll 4
    for (int h = 0; h < 256; ++h) {
        const float2 ek = *(const float2*)(ekp + (size_t)h * 1024);
        const float w = wv_s[h];
        cw += w;
        #pragma unroll
        for (int q = 0; q < 4; ++q) {
            const float eq = eq_s[q * 256 + h];
            const float d0 = fmaf(eq, ek.x, 1.f);
            const float d1 = fmaf(eq, ek.y, 1.f);
            acc[q][0] = fmaf(w, __builtin_amdgcn_rcpf(d0), acc[q][0]);
            acc[q][1] = fmaf(w, __builtin_amdgcn_rcpf(d1), acc[q][1]);
        }
    }

    const int vlen = valid_len[b];
    const int k0 = tid * 2;
    const bool v0 = (k0 < vlen), v1 = (k0 + 1 < vlen);

    float s[4][2], m[4];
    #pragma unroll
    for (int q = 0; q < 4; ++q) {
        s[q][0] = fmaf(-2.f, acc[q][0], cw);
        s[q][1] = fmaf(-2.f, acc[q][1], cw);
        float mm = -1e30f;
        if (v0) mm = s[q][0];
        if (v1) mm = fmaxf(mm, s[q][1]);
        m[q] = mm;
    }
    #pragma unroll
    for (int o = 32; o; o >>= 1) {
        #pragma unroll
        for (int q = 0; q < 4; ++q) m[q] = fmaxf(m[q], __shfl_xor(m[q], o));
    }
    const int wid = tid >> 6;
    if ((tid & 63) == 0) {
        #pragma unroll
        for (int q = 0; q < 4; ++q) red[wid][q] = m[q];
    }
    __syncthreads();
    #pragma unroll
    for (int q = 0; q < 4; ++q) {
        float mm = red[0][q];
        #pragma unroll
        for (int w = 1; w < 8; ++w) mm = fmaxf(mm, red[w][q]);
        m[q] = mm;
    }
    __syncthreads();

    float p[4][2], l[4];
    #pragma unroll
    for (int q = 0; q < 4; ++q) {
        p[q][0] = v0 ? __builtin_amdgcn_exp2f((s[q][0] - m[q]) * LOG2E) : 0.f;
        p[q][1] = v1 ? __builtin_amdgcn_exp2f((s[q][1] - m[q]) * LOG2E) : 0.f;
        l[q] = p[q][0] + p[q][1];
    }
    #pragma unroll
    for (int o = 32; o; o >>= 1) {
        #pragma unroll
        for (int q = 0; q < 4; ++q) l[q] += __shfl_xor(l[q], o);
    }
    if ((tid & 63) == 0) {
        #pragma unroll
        for (int q = 0; q < 4; ++q) red[wid][q] = l[q];
    }
    __syncthreads();
    #pragma unroll
    for (int q = 0; q < 4; ++q) {
        float ss = red[0][q];
        #pragma unroll
        for (int w = 1; w < 8; ++w) ss += red[w][q];
        const float rl = __builtin_amdgcn_rcpf(ss);
        float2 o;
        o.x = p[q][0] * rl;
        o.y = p[q][1] * rl;
        *(float2*)(attn + (size_t)(b * 256 + q0 + q) * 1024 + k0) = o;
    }
}

// ---------------------------------------------------------------------------
// Kernel D: out[b] = attn[b] @ value[b]   (f32 GEMM, 32x64 tile, K=1024)
// grid (8 n-tiles, 8 m-tiles, 4 b), 256 threads, micro 2x4
// ---------------------------------------------------------------------------
__global__ __launch_bounds__(256) void pv_kernel(
    const float* __restrict__ attn, const float* __restrict__ value,
    float* __restrict__ out)
{
    __shared__ float As[16][34];   // [k][m] padded, float2-aligned rows
    __shared__ float Bs[16][64];

    const int tid = threadIdx.x;
    const int b = blockIdx.z;
    const int m0 = blockIdx.y * 32, n0 = blockIdx.x * 64;
    const float* A = attn + (size_t)b * 256 * 1024 + (size_t)m0 * 1024;
    const float* B = value + (size_t)b * 1024 * 512;

    const int tx = tid & 15, ty = tid >> 4;        // ty 0..15 -> 2 m's each
    const int lr = tid >> 3, lc = (tid & 7) * 2;   // A-tile 32 x 16
    const int br = tid >> 4, bc = (tid & 15) * 4;  // B-tile 16 x 64

    float c[2][4] = {};

    for (int kt = 0; kt < 1024; kt += 16) {
        const float2 av = *(const float2*)(A + (size_t)lr * 1024 + kt + lc);
        const float4 bv = *(const float4*)(B + (size_t)(kt + br) * 512 + n0 + bc);
        __syncthreads();
        As[lc][lr] = av.x; As[lc + 1][lr] = av.y;
        *(float4*)&Bs[br][bc] = bv;
        __syncthreads();
        #pragma unroll
        for (int k = 0; k < 16; ++k) {
            const float2 a = *(const float2*)&As[k][ty * 2];
            const float4 bb = *(const float4*)&Bs[k][tx * 4];
            c[0][0] = fmaf(a.x, bb.x, c[0][0]);
            c[0][1] = fmaf(a.x, bb.y, c[0][1]);
            c[0][2] = fmaf(a.x, bb.z, c[0][2]);
            c[0][3] = fmaf(a.x, bb.w, c[0][3]);
            c[1][0] = fmaf(a.y, bb.x, c[1][0]);
            c[1][1] = fmaf(a.y, bb.y, c[1][1]);
            c[1][2] = fmaf(a.y, bb.z, c[1][2]);
            c[1][3] = fmaf(a.y, bb.w, c[1][3]);
        }
    }

    #pragma unroll
    for (int i = 0; i < 2; ++i) {
        float4 o;
        o.x = c[i][0]; o.y = c[i][1]; o.z = c[i][2]; o.w = c[i][3];
        *(float4*)(out + (size_t)b * 256 * 512 +
                   (size_t)(m0 + ty * 2 + i) * 512 + n0 + tx * 4) = o;
    }
}

// ---------------------------------------------------------------------------
extern "C" void kernel_launch(void* const* d_in, const int* in_sizes, int n_in,
                              void* d_out, int out_size, void* d_ws, size_t ws_size,
                              hipStream_t stream)
{
    const float* query = (const float*)d_in[0];   // [4,256,512]
    const float* key   = (const float*)d_in[1];   // [4,1024,512]
    const float* value = (const float*)d_in[2];   // [4,1024,512]
    const int*   vlen  = (const int*)d_in[3];     // [4]
    const float* Wq    = (const float*)d_in[4];   // [512,256]
    const float* Wk    = (const float*)d_in[5];   // [512,256]
    const float* wv    = (const float*)d_in[6];   // [256]
    float* out = (float*)d_out;                   // [4,256,512]

    float* Eq   = (float*)d_ws;                   // 1024*256        = 262144 f
    float* EkT  = Eq + 262144;                    // 4*256*1024      = 1048576 f
    float* attn = EkT + 1048576;                  // 4*256*1024      = 1048576 f

    hipLaunchKernelGGL(proj_kernel, dim3(4, 80), dim3(256), 0, stream,
                       query, key, Wq, Wk, Eq, EkT);
    hipLaunchKernelGGL(score_softmax_kernel, dim3(256), dim3(512), 0, stream,
                       Eq, EkT, wv, vlen, attn);
    hipLaunchKernelGGL(pv_kernel, dim3(8, 8, 4), dim3(256), 0, stream,
                       attn, value, out);
}

// Round 3
// 91.331 us; speedup vs baseline: 1.3213x; 1.3213x over previous
//
#include <hip/hip_runtime.h>

#define TWO_LOG2E 2.8853900817779268f   // 2*log2(e)
#define LOG2E     1.4426950408889634f

// ---------------------------------------------------------------------------
// Kernel P: fused Q/K projection GEMM, epilogue E = exp(2*proj)
//   rows 0..1023   : q-proj (query @ Wq)  -> Eq[row][h]        (row-major)
//   rows 1024..5119: k-proj (key @ Wk)    -> EkT[b][h][k]      (transposed)
// 64x64 tile, K=512 in steps of 16, register-prefetch pipelined.
// Key-blocks fully beyond valid_len[b] exit immediately (EkT never read there).
// ---------------------------------------------------------------------------
__global__ __launch_bounds__(256) void proj_kernel(
    const float* __restrict__ query, const float* __restrict__ key,
    const float* __restrict__ Wq, const float* __restrict__ Wk,
    const int* __restrict__ valid_len,
    float* __restrict__ Eq, float* __restrict__ EkT)
{
    __shared__ float lds[64 * 66];                 // 16.5 KiB, unioned
    float (*As)[68] = (float(*)[68])lds;           // [16][68]  (k-major, padded)
    float (*Bs)[64] = (float(*)[64])(lds + 16 * 68);

    const int tid = threadIdx.x;
    const int tx = tid & 15, ty = tid >> 4;
    const int m0 = blockIdx.y * 64, n0 = blockIdx.x * 64;
    const bool isq = (m0 < 1024);

    if (!isq) {
        const int krow0 = m0 - 1024;
        const int b = krow0 >> 10, kk0 = krow0 & 1023;
        if (kk0 >= valid_len[b]) return;           // uniform per block
    }

    const float* Ap = isq ? (query + (size_t)m0 * 512)
                          : (key + (size_t)(m0 - 1024) * 512);
    const float* Bp = isq ? Wq : Wk;

    const int lr = tid >> 2, lc = (tid & 3) * 4;   // A-tile: 64 rows x 16 k
    const int br = tid >> 4, bc = (tid & 15) * 4;  // B-tile: 16 k x 64 n

    float4 av = *(const float4*)(Ap + (size_t)lr * 512 + lc);
    float4 bv = *(const float4*)(Bp + (size_t)br * 256 + n0 + bc);

    float c[4][4] = {};

    for (int kt = 0; kt < 512; kt += 16) {
        __syncthreads();
        As[lc + 0][lr] = av.x; As[lc + 1][lr] = av.y;
        As[lc + 2][lr] = av.z; As[lc + 3][lr] = av.w;
        *(float4*)&Bs[br][bc] = bv;
        __syncthreads();
        if (kt + 16 < 512) {                       // prefetch next K-slab
            av = *(const float4*)(Ap + (size_t)lr * 512 + kt + 16 + lc);
            bv = *(const float4*)(Bp + (size_t)(kt + 16 + br) * 256 + n0 + bc);
        }
        #pragma unroll
        for (int k = 0; k < 16; ++k) {
            const float4 a = *(const float4*)&As[k][ty * 4];
            const float4 bb = *(const float4*)&Bs[k][tx * 4];
            const float ar[4] = {a.x, a.y, a.z, a.w};
            const float brr[4] = {bb.x, bb.y, bb.z, bb.w};
            #pragma unroll
            for (int i = 0; i < 4; ++i)
                #pragma unroll
                for (int j = 0; j < 4; ++j)
                    c[i][j] = fmaf(ar[i], brr[j], c[i][j]);
        }
    }

    if (isq) {
        #pragma unroll
        for (int i = 0; i < 4; ++i) {
            float4 o;
            o.x = __builtin_amdgcn_exp2f(c[i][0] * TWO_LOG2E);
            o.y = __builtin_amdgcn_exp2f(c[i][1] * TWO_LOG2E);
            o.z = __builtin_amdgcn_exp2f(c[i][2] * TWO_LOG2E);
            o.w = __builtin_amdgcn_exp2f(c[i][3] * TWO_LOG2E);
            *(float4*)(Eq + (size_t)(m0 + ty * 4 + i) * 256 + n0 + tx * 4) = o;
        }
    } else {
        __syncthreads();                            // done with As/Bs
        float (*Ct)[66] = (float(*)[66])lds;        // [64 h][66] transposed tile
        #pragma unroll
        for (int i = 0; i < 4; ++i)
            #pragma unroll
            for (int j = 0; j < 4; ++j)
                Ct[tx * 4 + j][ty * 4 + i] =
                    __builtin_amdgcn_exp2f(c[i][j] * TWO_LOG2E);
        __syncthreads();
        const int krow0 = m0 - 1024;
        const int b = krow0 >> 10, kk0 = krow0 & 1023;
        const int hr = tid >> 2, mc = (tid & 3) * 4;
        #pragma unroll
        for (int rep = 0; rep < 4; ++rep) {
            const int m = mc + rep * 16;
            float4 o;
            o.x = Ct[hr][m]; o.y = Ct[hr][m + 1];
            o.z = Ct[hr][m + 2]; o.w = Ct[hr][m + 3];
            *(float4*)(EkT + (size_t)(b * 256 + n0 + hr) * 1024 + kk0 + m) = o;
        }
    }
}

// ---------------------------------------------------------------------------
// Kernel C: score + masked softmax.
// score[b,q,k] = sum_h wv[h]*tanh(qp+kp) = C1 - 2*sum_h wv[h]*rcp(Eq*Ek + 1)
// block = (b, 4 q-rows); 512 threads; thread owns k = 2*tid, 2*tid+1.
// Waves fully beyond valid_len skip the 256-h loop (their attn is exactly 0).
// ---------------------------------------------------------------------------
__global__ __launch_bounds__(512) void score_softmax_kernel(
    const float* __restrict__ Eq, const float* __restrict__ EkT,
    const float* __restrict__ wv, const int* __restrict__ valid_len,
    float* __restrict__ attn)
{
    __shared__ float wv_s[256];
    __shared__ float eq_s[1024];     // 4 q rows x 256 h
    __shared__ float red[8][4];

    const int tid = threadIdx.x;
    const int b = blockIdx.x >> 6;
    const int q0 = (blockIdx.x & 63) << 2;

    const int vlen = valid_len[b];
    const int k0 = tid * 2;
    const bool v0 = (k0 < vlen), v1 = (k0 + 1 < vlen);

    if (tid < 256) wv_s[tid] = wv[tid];
    *(float2*)&eq_s[tid * 2] =
        *(const float2*)(Eq + (size_t)(b * 256 + q0) * 256 + tid * 2);
    __syncthreads();

    float acc[4][2] = {};
    float cw = 0.f;

    if (v0) {   // whole waves with k0 >= vlen skip the h-loop entirely
        const float* ekp = EkT + (size_t)(b * 256) * 1024 + k0;
        #pragma unroll 4
        for (int h = 0; h < 256; ++h) {
            const float2 ek = *(const float2*)(ekp + (size_t)h * 1024);
            const float w = wv_s[h];
            cw += w;
            #pragma unroll
            for (int q = 0; q < 4; ++q) {
                const float eq = eq_s[q * 256 + h];
                const float d0 = fmaf(eq, ek.x, 1.f);
                const float d1 = fmaf(eq, ek.y, 1.f);
                acc[q][0] = fmaf(w, __builtin_amdgcn_rcpf(d0), acc[q][0]);
                acc[q][1] = fmaf(w, __builtin_amdgcn_rcpf(d1), acc[q][1]);
            }
        }
    }

    float s[4][2], m[4];
    #pragma unroll
    for (int q = 0; q < 4; ++q) {
        s[q][0] = fmaf(-2.f, acc[q][0], cw);
        s[q][1] = fmaf(-2.f, acc[q][1], cw);
        float mm = -1e30f;
        if (v0) mm = s[q][0];
        if (v1) mm = fmaxf(mm, s[q][1]);
        m[q] = mm;
    }
    #pragma unroll
    for (int o = 32; o; o >>= 1) {
        #pragma unroll
        for (int q = 0; q < 4; ++q) m[q] = fmaxf(m[q], __shfl_xor(m[q], o));
    }
    const int wid = tid >> 6;
    if ((tid & 63) == 0) {
        #pragma unroll
        for (int q = 0; q < 4; ++q) red[wid][q] = m[q];
    }
    __syncthreads();
    #pragma unroll
    for (int q = 0; q < 4; ++q) {
        float mm = red[0][q];
        #pragma unroll
        for (int w = 1; w < 8; ++w) mm = fmaxf(mm, red[w][q]);
        m[q] = mm;
    }
    __syncthreads();

    float p[4][2], l[4];
    #pragma unroll
    for (int q = 0; q < 4; ++q) {
        p[q][0] = v0 ? __builtin_amdgcn_exp2f((s[q][0] - m[q]) * LOG2E) : 0.f;
        p[q][1] = v1 ? __builtin_amdgcn_exp2f((s[q][1] - m[q]) * LOG2E) : 0.f;
        l[q] = p[q][0] + p[q][1];
    }
    #pragma unroll
    for (int o = 32; o; o >>= 1) {
        #pragma unroll
        for (int q = 0; q < 4; ++q) l[q] += __shfl_xor(l[q], o);
    }
    if ((tid & 63) == 0) {
        #pragma unroll
        for (int q = 0; q < 4; ++q) red[wid][q] = l[q];
    }
    __syncthreads();
    #pragma unroll
    for (int q = 0; q < 4; ++q) {
        float ss = red[0][q];
        #pragma unroll
        for (int w = 1; w < 8; ++w) ss += red[w][q];
        const float rl = __builtin_amdgcn_rcpf(ss);
        float2 o;
        o.x = p[q][0] * rl;
        o.y = p[q][1] * rl;
        *(float2*)(attn + (size_t)(b * 256 + q0 + q) * 1024 + k0) = o;
    }
}

// ---------------------------------------------------------------------------
// Kernel D: out[b] = attn[b] @ value[b]   (f32 GEMM, 32x64 tile, BK=32)
// Register-prefetch pipelined; K-loop bounded by ceil(valid_len/32)
// (attn is exactly 0 beyond valid_len). grid (8 n, 8 m, 4 b), 256 threads.
// ---------------------------------------------------------------------------
__global__ __launch_bounds__(256) void pv_kernel(
    const float* __restrict__ attn, const float* __restrict__ value,
    const int* __restrict__ valid_len,
    float* __restrict__ out)
{
    __shared__ float As[32][34];   // [k][m], even-padded so float2 reads align
    __shared__ float Bs[32][64];

    const int tid = threadIdx.x;
    const int b = blockIdx.z;
    const int m0 = blockIdx.y * 32, n0 = blockIdx.x * 64;
    const float* A = attn + ((size_t)b * 256 + m0) * 1024;
    const float* B = value + (size_t)b * 1024 * 512;

    const int kend = (valid_len[b] + 31) & ~31;    // >= 32 since vlen >= 1

    const int tx = tid & 15, ty = tid >> 4;        // micro 2m x 4n
    const int lr = tid >> 3, lc = (tid & 7) * 4;   // A-tile 32 m x 32 k
    const int br = tid >> 4, bc = (tid & 15) * 4;  // B-tile (16+16) k x 64 n

    float4 av  = *(const float4*)(A + (size_t)lr * 1024 + lc);
    float4 bv0 = *(const float4*)(B + (size_t)br * 512 + n0 + bc);
    float4 bv1 = *(const float4*)(B + (size_t)(br + 16) * 512 + n0 + bc);

    float c[2][4] = {};

    for (int kt = 0; kt < kend; kt += 32) {
        __syncthreads();
        As[lc + 0][lr] = av.x; As[lc + 1][lr] = av.y;
        As[lc + 2][lr] = av.z; As[lc + 3][lr] = av.w;
        *(float4*)&Bs[br][bc] = bv0;
        *(float4*)&Bs[br + 16][bc] = bv1;
        __syncthreads();
        if (kt + 32 < kend) {                      // prefetch next K-slab
            av  = *(const float4*)(A + (size_t)lr * 1024 + kt + 32 + lc);
            bv0 = *(const float4*)(B + (size_t)(kt + 32 + br) * 512 + n0 + bc);
            bv1 = *(const float4*)(B + (size_t)(kt + 48 + br) * 512 + n0 + bc);
        }
        #pragma unroll
        for (int k = 0; k < 32; ++k) {
            const float2 a = *(const float2*)&As[k][ty * 2];
            const float4 bb = *(const float4*)&Bs[k][tx * 4];
            c[0][0] = fmaf(a.x, bb.x, c[0][0]);
            c[0][1] = fmaf(a.x, bb.y, c[0][1]);
            c[0][2] = fmaf(a.x, bb.z, c[0][2]);
            c[0][3] = fmaf(a.x, bb.w, c[0][3]);
            c[1][0] = fmaf(a.y, bb.x, c[1][0]);
            c[1][1] = fmaf(a.y, bb.y, c[1][1]);
            c[1][2] = fmaf(a.y, bb.z, c[1][2]);
            c[1][3] = fmaf(a.y, bb.w, c[1][3]);
        }
    }

    #pragma unroll
    for (int i = 0; i < 2; ++i) {
        float4 o;
        o.x = c[i][0]; o.y = c[i][1]; o.z = c[i][2]; o.w = c[i][3];
        *(float4*)(out + (size_t)b * 256 * 512 +
                   (size_t)(m0 + ty * 2 + i) * 512 + n0 + tx * 4) = o;
    }
}

// ---------------------------------------------------------------------------
extern "C" void kernel_launch(void* const* d_in, const int* in_sizes, int n_in,
                              void* d_out, int out_size, void* d_ws, size_t ws_size,
                              hipStream_t stream)
{
    const float* query = (const float*)d_in[0];   // [4,256,512]
    const float* key   = (const float*)d_in[1];   // [4,1024,512]
    const float* value = (const float*)d_in[2];   // [4,1024,512]
    const int*   vlen  = (const int*)d_in[3];     // [4]
    const float* Wq    = (const float*)d_in[4];   // [512,256]
    const float* Wk    = (const float*)d_in[5];   // [512,256]
    const float* wv    = (const float*)d_in[6];   // [256]
    float* out = (float*)d_out;                   // [4,256,512]

    float* Eq   = (float*)d_ws;                   // 1024*256        = 262144 f
    float* EkT  = Eq + 262144;                    // 4*256*1024      = 1048576 f
    float* attn = EkT + 1048576;                  // 4*256*1024      = 1048576 f

    hipLaunchKernelGGL(proj_kernel, dim3(4, 80), dim3(256), 0, stream,
                       query, key, Wq, Wk, vlen, Eq, EkT);
    hipLaunchKernelGGL(score_softmax_kernel, dim3(256), dim3(512), 0, stream,
                       Eq, EkT, wv, vlen, attn);
    hipLaunchKernelGGL(pv_kernel, dim3(8, 8, 4), dim3(256), 0, stream,
                       attn, value, vlen, out);
}

// Round 4
// 85.411 us; speedup vs baseline: 1.4129x; 1.0693x over previous
//
#include <hip/hip_runtime.h>

#define TWO_LOG2E 2.8853900817779268f   // 2*log2(e)
#define LOG2E     1.4426950408889634f

// ---------------------------------------------------------------------------
// Kernel P: fused Q/K projection GEMM, epilogue E = exp(2*proj)
//   rows 0..1023   : q-proj (query @ Wq)  -> Eq[row][h]        (row-major)
//   rows 1024..5119: k-proj (key @ Wk)    -> EkT[b][h][k]      (transposed)
// 64x64 tile, K=512 in steps of 16, register-prefetch pipelined.
// Key-blocks fully beyond valid_len[b] exit immediately (EkT never read there).
// ---------------------------------------------------------------------------
__global__ __launch_bounds__(256) void proj_kernel(
    const float* __restrict__ query, const float* __restrict__ key,
    const float* __restrict__ Wq, const float* __restrict__ Wk,
    const int* __restrict__ valid_len,
    float* __restrict__ Eq, float* __restrict__ EkT)
{
    __shared__ float lds[64 * 66];                 // 16.5 KiB, unioned
    float (*As)[68] = (float(*)[68])lds;           // [16][68]  (k-major, padded)
    float (*Bs)[64] = (float(*)[64])(lds + 16 * 68);

    const int tid = threadIdx.x;
    const int tx = tid & 15, ty = tid >> 4;
    const int m0 = blockIdx.y * 64, n0 = blockIdx.x * 64;
    const bool isq = (m0 < 1024);

    if (!isq) {
        const int krow0 = m0 - 1024;
        const int b = krow0 >> 10, kk0 = krow0 & 1023;
        if (kk0 >= valid_len[b]) return;           // uniform per block
    }

    const float* Ap = isq ? (query + (size_t)m0 * 512)
                          : (key + (size_t)(m0 - 1024) * 512);
    const float* Bp = isq ? Wq : Wk;

    const int lr = tid >> 2, lc = (tid & 3) * 4;   // A-tile: 64 rows x 16 k
    const int br = tid >> 4, bc = (tid & 15) * 4;  // B-tile: 16 k x 64 n

    float4 av = *(const float4*)(Ap + (size_t)lr * 512 + lc);
    float4 bv = *(const float4*)(Bp + (size_t)br * 256 + n0 + bc);

    float c[4][4] = {};

    for (int kt = 0; kt < 512; kt += 16) {
        __syncthreads();
        As[lc + 0][lr] = av.x; As[lc + 1][lr] = av.y;
        As[lc + 2][lr] = av.z; As[lc + 3][lr] = av.w;
        *(float4*)&Bs[br][bc] = bv;
        __syncthreads();
        if (kt + 16 < 512) {                       // prefetch next K-slab
            av = *(const float4*)(Ap + (size_t)lr * 512 + kt + 16 + lc);
            bv = *(const float4*)(Bp + (size_t)(kt + 16 + br) * 256 + n0 + bc);
        }
        #pragma unroll
        for (int k = 0; k < 16; ++k) {
            const float4 a = *(const float4*)&As[k][ty * 4];
            const float4 bb = *(const float4*)&Bs[k][tx * 4];
            const float ar[4] = {a.x, a.y, a.z, a.w};
            const float brr[4] = {bb.x, bb.y, bb.z, bb.w};
            #pragma unroll
            for (int i = 0; i < 4; ++i)
                #pragma unroll
                for (int j = 0; j < 4; ++j)
                    c[i][j] = fmaf(ar[i], brr[j], c[i][j]);
        }
    }

    if (isq) {
        #pragma unroll
        for (int i = 0; i < 4; ++i) {
            float4 o;
            o.x = __builtin_amdgcn_exp2f(c[i][0] * TWO_LOG2E);
            o.y = __builtin_amdgcn_exp2f(c[i][1] * TWO_LOG2E);
            o.z = __builtin_amdgcn_exp2f(c[i][2] * TWO_LOG2E);
            o.w = __builtin_amdgcn_exp2f(c[i][3] * TWO_LOG2E);
            *(float4*)(Eq + (size_t)(m0 + ty * 4 + i) * 256 + n0 + tx * 4) = o;
        }
    } else {
        __syncthreads();                            // done with As/Bs
        float (*Ct)[66] = (float(*)[66])lds;        // [64 h][66] transposed tile
        #pragma unroll
        for (int i = 0; i < 4; ++i)
            #pragma unroll
            for (int j = 0; j < 4; ++j)
                Ct[tx * 4 + j][ty * 4 + i] =
                    __builtin_amdgcn_exp2f(c[i][j] * TWO_LOG2E);
        __syncthreads();
        const int krow0 = m0 - 1024;
        const int b = krow0 >> 10, kk0 = krow0 & 1023;
        const int hr = tid >> 2, mc = (tid & 3) * 4;
        #pragma unroll
        for (int rep = 0; rep < 4; ++rep) {
            const int m = mc + rep * 16;
            float4 o;
            o.x = Ct[hr][m]; o.y = Ct[hr][m + 1];
            o.z = Ct[hr][m + 2]; o.w = Ct[hr][m + 3];
            *(float4*)(EkT + (size_t)(b * 256 + n0 + hr) * 1024 + kk0 + m) = o;
        }
    }
}

// ---------------------------------------------------------------------------
// Kernel C: score + masked softmax.
// score[b,q,k] = sum_h wv[h]*tanh(qp+kp) = C1 - 2*sum_h wv[h]*rcp(Eq*Ek + 1)
// block = (b, 4 q-rows); 1024 threads; thread owns k = tid.
// Eq tile staged TRANSPOSED in LDS as float4 [h][4q] -> one ds_read_b128
// broadcast per h. Waves fully beyond valid_len skip the 256-h loop.
// ---------------------------------------------------------------------------
__global__ __launch_bounds__(1024) void score_softmax_kernel(
    const float* __restrict__ Eq, const float* __restrict__ EkT,
    const float* __restrict__ wv, const int* __restrict__ valid_len,
    float* __restrict__ attn)
{
    __shared__ float wv_s[256];
    __shared__ float eq4_s[256 * 4];   // [h][q]
    __shared__ float red[16][4];

    const int tid = threadIdx.x;
    const int b = blockIdx.x >> 6;
    const int q0 = (blockIdx.x & 63) << 2;

    const int vlen = valid_len[b];
    const int k = tid;
    const bool v = (k < vlen);

    if (tid < 256) wv_s[tid] = wv[tid];
    {
        const int q = tid >> 8, h = tid & 255;     // coalesced global read
        eq4_s[h * 4 + q] = Eq[(size_t)(b * 256 + q0 + q) * 256 + h];
    }
    __syncthreads();

    float acc[4] = {};
    float cw = 0.f;

    if (v) {   // whole waves with k >= vlen skip the h-loop entirely
        const float* ekp = EkT + (size_t)(b * 256) * 1024 + k;
        #pragma unroll 8
        for (int h = 0; h < 256; ++h) {
            const float ek = ekp[(size_t)h * 1024];
            const float4 eq = *(const float4*)&eq4_s[h * 4];
            const float w = wv_s[h];
            cw += w;
            acc[0] = fmaf(w, __builtin_amdgcn_rcpf(fmaf(eq.x, ek, 1.f)), acc[0]);
            acc[1] = fmaf(w, __builtin_amdgcn_rcpf(fmaf(eq.y, ek, 1.f)), acc[1]);
            acc[2] = fmaf(w, __builtin_amdgcn_rcpf(fmaf(eq.z, ek, 1.f)), acc[2]);
            acc[3] = fmaf(w, __builtin_amdgcn_rcpf(fmaf(eq.w, ek, 1.f)), acc[3]);
        }
    }

    float s[4], m[4];
    #pragma unroll
    for (int q = 0; q < 4; ++q) {
        s[q] = fmaf(-2.f, acc[q], cw);
        m[q] = v ? s[q] : -1e30f;
    }
    #pragma unroll
    for (int o = 32; o; o >>= 1) {
        #pragma unroll
        for (int q = 0; q < 4; ++q) m[q] = fmaxf(m[q], __shfl_xor(m[q], o));
    }
    const int wid = tid >> 6;
    if ((tid & 63) == 0) {
        #pragma unroll
        for (int q = 0; q < 4; ++q) red[wid][q] = m[q];
    }
    __syncthreads();
    #pragma unroll
    for (int q = 0; q < 4; ++q) {
        float mm = red[0][q];
        #pragma unroll
        for (int w = 1; w < 16; ++w) mm = fmaxf(mm, red[w][q]);
        m[q] = mm;
    }
    __syncthreads();

    float p[4], l[4];
    #pragma unroll
    for (int q = 0; q < 4; ++q) {
        p[q] = v ? __builtin_amdgcn_exp2f((s[q] - m[q]) * LOG2E) : 0.f;
        l[q] = p[q];
    }
    #pragma unroll
    for (int o = 32; o; o >>= 1) {
        #pragma unroll
        for (int q = 0; q < 4; ++q) l[q] += __shfl_xor(l[q], o);
    }
    if ((tid & 63) == 0) {
        #pragma unroll
        for (int q = 0; q < 4; ++q) red[wid][q] = l[q];
    }
    __syncthreads();
    #pragma unroll
    for (int q = 0; q < 4; ++q) {
        float ss = red[0][q];
        #pragma unroll
        for (int w = 1; w < 16; ++w) ss += red[w][q];
        const float rl = __builtin_amdgcn_rcpf(ss);
        attn[(size_t)(b * 256 + q0 + q) * 1024 + k] = p[q] * rl;
    }
}

// ---------------------------------------------------------------------------
// Kernel D: out[b] = attn[b] @ value[b]   (f32 GEMM, 32x64 tile, BK=32)
// Register-prefetch pipelined; K-loop bounded by ceil(valid_len/32)
// (attn is exactly 0 beyond valid_len). grid (8 n, 8 m, 4 b), 256 threads.
// ---------------------------------------------------------------------------
__global__ __launch_bounds__(256) void pv_kernel(
    const float* __restrict__ attn, const float* __restrict__ value,
    const int* __restrict__ valid_len,
    float* __restrict__ out)
{
    __shared__ float As[32][34];   // [k][m], even-padded so float2 reads align
    __shared__ float Bs[32][64];

    const int tid = threadIdx.x;
    const int b = blockIdx.z;
    const int m0 = blockIdx.y * 32, n0 = blockIdx.x * 64;
    const float* A = attn + ((size_t)b * 256 + m0) * 1024;
    const float* B = value + (size_t)b * 1024 * 512;

    const int kend = (valid_len[b] + 31) & ~31;    // >= 32 since vlen >= 1

    const int tx = tid & 15, ty = tid >> 4;        // micro 2m x 4n
    const int lr = tid >> 3, lc = (tid & 7) * 4;   // A-tile 32 m x 32 k
    const int br = tid >> 4, bc = (tid & 15) * 4;  // B-tile (16+16) k x 64 n

    float4 av  = *(const float4*)(A + (size_t)lr * 1024 + lc);
    float4 bv0 = *(const float4*)(B + (size_t)br * 512 + n0 + bc);
    float4 bv1 = *(const float4*)(B + (size_t)(br + 16) * 512 + n0 + bc);

    float c[2][4] = {};

    for (int kt = 0; kt < kend; kt += 32) {
        __syncthreads();
        As[lc + 0][lr] = av.x; As[lc + 1][lr] = av.y;
        As[lc + 2][lr] = av.z; As[lc + 3][lr] = av.w;
        *(float4*)&Bs[br][bc] = bv0;
        *(float4*)&Bs[br + 16][bc] = bv1;
        __syncthreads();
        if (kt + 32 < kend) {                      // prefetch next K-slab
            av  = *(const float4*)(A + (size_t)lr * 1024 + kt + 32 + lc);
            bv0 = *(const float4*)(B + (size_t)(kt + 32 + br) * 512 + n0 + bc);
            bv1 = *(const float4*)(B + (size_t)(kt + 48 + br) * 512 + n0 + bc);
        }
        #pragma unroll
        for (int k = 0; k < 32; ++k) {
            const float2 a = *(const float2*)&As[k][ty * 2];
            const float4 bb = *(const float4*)&Bs[k][tx * 4];
            c[0][0] = fmaf(a.x, bb.x, c[0][0]);
            c[0][1] = fmaf(a.x, bb.y, c[0][1]);
            c[0][2] = fmaf(a.x, bb.z, c[0][2]);
            c[0][3] = fmaf(a.x, bb.w, c[0][3]);
            c[1][0] = fmaf(a.y, bb.x, c[1][0]);
            c[1][1] = fmaf(a.y, bb.y, c[1][1]);
            c[1][2] = fmaf(a.y, bb.z, c[1][2]);
            c[1][3] = fmaf(a.y, bb.w, c[1][3]);
        }
    }

    #pragma unroll
    for (int i = 0; i < 2; ++i) {
        float4 o;
        o.x = c[i][0]; o.y = c[i][1]; o.z = c[i][2]; o.w = c[i][3];
        *(float4*)(out + (size_t)b * 256 * 512 +
                   (size_t)(m0 + ty * 2 + i) * 512 + n0 + tx * 4) = o;
    }
}

// ---------------------------------------------------------------------------
extern "C" void kernel_launch(void* const* d_in, const int* in_sizes, int n_in,
                              void* d_out, int out_size, void* d_ws, size_t ws_size,
                              hipStream_t stream)
{
    const float* query = (const float*)d_in[0];   // [4,256,512]
    const float* key   = (const float*)d_in[1];   // [4,1024,512]
    const float* value = (const float*)d_in[2];   // [4,1024,512]
    const int*   vlen  = (const int*)d_in[3];     // [4]
    const float* Wq    = (const float*)d_in[4];   // [512,256]
    const float* Wk    = (const float*)d_in[5];   // [512,256]
    const float* wv    = (const float*)d_in[6];   // [256]
    float* out = (float*)d_out;                   // [4,256,512]

    float* Eq   = (float*)d_ws;                   // 1024*256        = 262144 f
    float* EkT  = Eq + 262144;                    // 4*256*1024      = 1048576 f
    float* attn = EkT + 1048576;                  // 4*256*1024      = 1048576 f

    hipLaunchKernelGGL(proj_kernel, dim3(4, 80), dim3(256), 0, stream,
                       query, key, Wq, Wk, vlen, Eq, EkT);
    hipLaunchKernelGGL(score_softmax_kernel, dim3(256), dim3(1024), 0, stream,
                       Eq, EkT, wv, vlen, attn);
    hipLaunchKernelGGL(pv_kernel, dim3(8, 8, 4), dim3(256), 0, stream,
                       attn, value, vlen, out);
}

// Round 5
// 84.063 us; speedup vs baseline: 1.4356x; 1.0160x over previous
//
#include <hip/hip_runtime.h>

typedef __attribute__((ext_vector_type(8))) short short8v;
typedef __attribute__((ext_vector_type(4))) float float4v;
typedef unsigned int uint;

#define TWO_LOG2E 2.8853900817779268f   // 2*log2(e)
#define LOG2E     1.4426950408889634f

// ---------------------------------------------------------------------------
// f32 -> bf16 helpers (RNE), packing pairs into uint words
// ---------------------------------------------------------------------------
__device__ inline uint rne_bf16(float x) {
    uint u = __float_as_uint(x);
    return (u + 0x7fffu + ((u >> 16) & 1u)) >> 16;
}
// hi = bf16(a), lo = bf16(a - f32(hi)); returns packed hi pair, sets lo pair
__device__ inline uint pack_hi_lo(float a0, float a1, uint& lo_pack) {
    const uint h0 = rne_bf16(a0), h1 = rne_bf16(a1);
    const float f0 = __uint_as_float(h0 << 16), f1 = __uint_as_float(h1 << 16);
    const float l0 = a0 - f0, l1 = a1 - f1;
    lo_pack = (rne_bf16(l1) << 16) | rne_bf16(l0);
    return (h1 << 16) | h0;
}

// ---------------------------------------------------------------------------
// prep_a: split A = [query(1024 rows); key(4096 rows)] x 512 into bf16 hi/lo.
// Thread handles 8 consecutive elements of one row. Key-rows in fully-skipped
// proj blocks (64-row granules beyond valid_len) are skipped.
// ---------------------------------------------------------------------------
__global__ __launch_bounds__(256) void prep_a(
    const float* __restrict__ query, const float* __restrict__ key,
    const int* __restrict__ vlen,
    ushort* __restrict__ A_hi, ushort* __restrict__ A_lo)
{
    const int t = blockIdx.x * 256 + threadIdx.x;   // 327680 total
    const int row = t >> 6;
    const int cg = (t & 63) * 8;
    if (row >= 1024) {
        const int kr = (row - 1024) & 1023, b = (row - 1024) >> 10;
        if ((kr & ~63) >= vlen[b]) return;
    }
    const float* src = (row < 1024) ? (query + (size_t)row * 512 + cg)
                                    : (key + (size_t)(row - 1024) * 512 + cg);
    const float4 x0 = *(const float4*)src;
    const float4 x1 = *(const float4*)(src + 4);
    uint h0, h1, h2, h3, l0, l1, l2, l3;
    h0 = pack_hi_lo(x0.x, x0.y, l0);
    h1 = pack_hi_lo(x0.z, x0.w, l1);
    h2 = pack_hi_lo(x1.x, x1.y, l2);
    h3 = pack_hi_lo(x1.z, x1.w, l3);
    *(uint4*)(A_hi + (size_t)row * 512 + cg) = make_uint4(h0, h1, h2, h3);
    *(uint4*)(A_lo + (size_t)row * 512 + cg) = make_uint4(l0, l1, l2, l3);
}

// ---------------------------------------------------------------------------
// prep_w: WT_hi/lo[w][n][k] = split(W_w[k][n]) — transpose + hi/lo split.
// ---------------------------------------------------------------------------
__global__ __launch_bounds__(256) void prep_w(
    const float* __restrict__ Wq, const float* __restrict__ Wk,
    ushort* __restrict__ WT_hi, ushort* __restrict__ WT_lo)
{
    const int t = blockIdx.x * 256 + threadIdx.x;   // 32768 total
    const int n = t & 255;
    const int kg = ((t >> 8) & 63) * 8;
    const int w = t >> 14;
    const float* W = w ? Wk : Wq;
    float x[8];
    #pragma unroll
    for (int i = 0; i < 8; ++i) x[i] = W[(size_t)(kg + i) * 256 + n];
    uint h0, h1, h2, h3, l0, l1, l2, l3;
    h0 = pack_hi_lo(x[0], x[1], l0);
    h1 = pack_hi_lo(x[2], x[3], l1);
    h2 = pack_hi_lo(x[4], x[5], l2);
    h3 = pack_hi_lo(x[6], x[7], l3);
    const size_t off = ((size_t)w * 256 + n) * 512 + kg;
    *(uint4*)(WT_hi + off) = make_uint4(h0, h1, h2, h3);
    *(uint4*)(WT_lo + off) = make_uint4(l0, l1, l2, l3);
}

// ---------------------------------------------------------------------------
// Kernel P (MFMA): proj via 3-MFMA hi/lo bf16 split (fp32-grade accuracy).
// 1 wave per block, wave tile 64m x 64n, K=512 in steps of 32, no LDS.
//   rows 0..1023   -> EqT[h][m]      (transposed, for score's float4 staging)
//   rows 1024..5119-> EkT[b][h][k]
// Epilogue applies E = exp2(C * 2log2e). Fragment layouts (gfx950 16x16x32):
//   A[i][k]: i=lane&15, k=(lane>>4)*8+e   (row-major A_hi/A_lo, b128 loads)
//   B[k][j]: j=lane&15, k=(lane>>4)*8+e   (WT[n][k] layout, b128 loads)
//   D[i][j]: j=lane&15, i=(lane>>4)*4+reg (float4 stores along m/k)
// ---------------------------------------------------------------------------
#define LOADF(s, kbase) { const int ko = (kbase) + half * 8;                              \
    _Pragma("unroll") for (int f = 0; f < 4; ++f) {                                       \
        ah##s[f] = *(const short8v*)(a_h + (size_t)(f * 16) * 512 + ko);                  \
        al##s[f] = *(const short8v*)(a_l + (size_t)(f * 16) * 512 + ko);                  \
        bh##s[f] = *(const short8v*)(wt_h + (size_t)(f * 16) * 512 + ko);                 \
        bl##s[f] = *(const short8v*)(wt_l + (size_t)(f * 16) * 512 + ko); } }

#define MFMAS(s)                                                                          \
    _Pragma("unroll") for (int mf = 0; mf < 4; ++mf)                                      \
    _Pragma("unroll") for (int nf = 0; nf < 4; ++nf) {                                    \
        acc[mf][nf] = __builtin_amdgcn_mfma_f32_16x16x32_bf16(ah##s[mf], bh##s[nf], acc[mf][nf], 0, 0, 0); \
        acc[mf][nf] = __builtin_amdgcn_mfma_f32_16x16x32_bf16(ah##s[mf], bl##s[nf], acc[mf][nf], 0, 0, 0); \
        acc[mf][nf] = __builtin_amdgcn_mfma_f32_16x16x32_bf16(al##s[mf], bh##s[nf], acc[mf][nf], 0, 0, 0); }

__global__ __launch_bounds__(64) void proj_mfma(
    const ushort* __restrict__ A_hi, const ushort* __restrict__ A_lo,
    const ushort* __restrict__ WT_hi, const ushort* __restrict__ WT_lo,
    const int* __restrict__ valid_len,
    float* __restrict__ EqT, float* __restrict__ EkT)
{
    const int lane = threadIdx.x;
    const int n0 = blockIdx.x * 64;
    const int m0 = blockIdx.y * 64;
    const bool isq = (m0 < 1024);
    int b = 0, kk0 = 0;
    if (!isq) {
        kk0 = (m0 - 1024) & 1023;
        b = (m0 - 1024) >> 10;
        if (kk0 >= valid_len[b]) return;
    }
    const int r = lane & 15, half = lane >> 4;
    const size_t wsel = isq ? 0 : (size_t)256 * 512;
    const ushort* wt_h = WT_hi + wsel + (size_t)(n0 + r) * 512;
    const ushort* wt_l = WT_lo + wsel + (size_t)(n0 + r) * 512;
    const ushort* a_h = A_hi + (size_t)(m0 + r) * 512;
    const ushort* a_l = A_lo + (size_t)(m0 + r) * 512;

    float4v acc[4][4] = {{{0.f}}};
    short8v ah0[4], al0[4], bh0[4], bl0[4];
    short8v ah1[4], al1[4], bh1[4], bl1[4];

    LOADF(0, 0);
    for (int kt = 0; kt < 512; kt += 64) {
        LOADF(1, kt + 32);
        MFMAS(0);
        if (kt + 64 < 512) LOADF(0, kt + 64);
        MFMAS(1);
    }

    #pragma unroll
    for (int mf = 0; mf < 4; ++mf) {
        #pragma unroll
        for (int nf = 0; nf < 4; ++nf) {
            float4v e;
            #pragma unroll
            for (int i = 0; i < 4; ++i)
                e[i] = __builtin_amdgcn_exp2f(acc[mf][nf][i] * TWO_LOG2E);
            if (isq) {
                *(float4v*)(EqT + (size_t)(n0 + nf * 16 + r) * 1024 +
                            m0 + mf * 16 + half * 4) = e;
            } else {
                *(float4v*)(EkT + (size_t)(b * 256 + n0 + nf * 16 + r) * 1024 +
                            kk0 + mf * 16 + half * 4) = e;
            }
        }
    }
}

// ---------------------------------------------------------------------------
// Kernel C: score + masked softmax.
// score[b,q,k] = C1 - 2*sum_h wv[h]*rcp(Eq*Ek + 1)
// block = (b, 4 q-rows); 1024 threads; thread owns k = tid.
// Eq staged from EqT[h][m] as one float4 per h. Waves beyond valid_len skip.
// ---------------------------------------------------------------------------
__global__ __launch_bounds__(1024) void score_softmax_kernel(
    const float* __restrict__ EqT, const float* __restrict__ EkT,
    const float* __restrict__ wv, const int* __restrict__ valid_len,
    float* __restrict__ attn)
{
    __shared__ float wv_s[256];
    __shared__ float eq4_s[256 * 4];   // [h][q]
    __shared__ float red[16][4];

    const int tid = threadIdx.x;
    const int b = blockIdx.x >> 6;
    const int q0 = (blockIdx.x & 63) << 2;

    const int vlen = valid_len[b];
    const int k = tid;
    const bool v = (k < vlen);

    if (tid < 256) {
        wv_s[tid] = wv[tid];
        *(float4*)&eq4_s[tid * 4] =
            *(const float4*)(EqT + (size_t)tid * 1024 + b * 256 + q0);
    }
    __syncthreads();

    float acc[4] = {};
    float cw = 0.f;

    if (v) {   // whole waves with k >= vlen skip the h-loop entirely
        const float* ekp = EkT + (size_t)(b * 256) * 1024 + k;
        #pragma unroll 8
        for (int h = 0; h < 256; ++h) {
            const float ek = ekp[(size_t)h * 1024];
            const float4 eq = *(const float4*)&eq4_s[h * 4];
            const float w = wv_s[h];
            cw += w;
            acc[0] = fmaf(w, __builtin_amdgcn_rcpf(fmaf(eq.x, ek, 1.f)), acc[0]);
            acc[1] = fmaf(w, __builtin_amdgcn_rcpf(fmaf(eq.y, ek, 1.f)), acc[1]);
            acc[2] = fmaf(w, __builtin_amdgcn_rcpf(fmaf(eq.z, ek, 1.f)), acc[2]);
            acc[3] = fmaf(w, __builtin_amdgcn_rcpf(fmaf(eq.w, ek, 1.f)), acc[3]);
        }
    }

    float s[4], m[4];
    #pragma unroll
    for (int q = 0; q < 4; ++q) {
        s[q] = fmaf(-2.f, acc[q], cw);
        m[q] = v ? s[q] : -1e30f;
    }
    #pragma unroll
    for (int o = 32; o; o >>= 1) {
        #pragma unroll
        for (int q = 0; q < 4; ++q) m[q] = fmaxf(m[q], __shfl_xor(m[q], o));
    }
    const int wid = tid >> 6;
    if ((tid & 63) == 0) {
        #pragma unroll
        for (int q = 0; q < 4; ++q) red[wid][q] = m[q];
    }
    __syncthreads();
    #pragma unroll
    for (int q = 0; q < 4; ++q) {
        float mm = red[0][q];
        #pragma unroll
        for (int w = 1; w < 16; ++w) mm = fmaxf(mm, red[w][q]);
        m[q] = mm;
    }
    __syncthreads();

    float p[4], l[4];
    #pragma unroll
    for (int q = 0; q < 4; ++q) {
        p[q] = v ? __builtin_amdgcn_exp2f((s[q] - m[q]) * LOG2E) : 0.f;
        l[q] = p[q];
    }
    #pragma unroll
    for (int o = 32; o; o >>= 1) {
        #pragma unroll
        for (int q = 0; q < 4; ++q) l[q] += __shfl_xor(l[q], o);
    }
    if ((tid & 63) == 0) {
        #pragma unroll
        for (int q = 0; q < 4; ++q) red[wid][q] = l[q];
    }
    __syncthreads();
    #pragma unroll
    for (int q = 0; q < 4; ++q) {
        float ss = red[0][q];
        #pragma unroll
        for (int w = 1; w < 16; ++w) ss += red[w][q];
        const float rl = __builtin_amdgcn_rcpf(ss);
        attn[(size_t)(b * 256 + q0 + q) * 1024 + k] = p[q] * rl;
    }
}

// ---------------------------------------------------------------------------
// Kernel D: out[b] = attn[b] @ value[b]   (f32 GEMM, 32x64 tile, BK=32)
// Register-prefetch pipelined; K-loop bounded by ceil(valid_len/32).
// ---------------------------------------------------------------------------
__global__ __launch_bounds__(256) void pv_kernel(
    const float* __restrict__ attn, const float* __restrict__ value,
    const int* __restrict__ valid_len,
    float* __restrict__ out)
{
    __shared__ float As[32][34];
    __shared__ float Bs[32][64];

    const int tid = threadIdx.x;
    const int b = blockIdx.z;
    const int m0 = blockIdx.y * 32, n0 = blockIdx.x * 64;
    const float* A = attn + ((size_t)b * 256 + m0) * 1024;
    const float* B = value + (size_t)b * 1024 * 512;

    const int kend = (valid_len[b] + 31) & ~31;

    const int tx = tid & 15, ty = tid >> 4;
    const int lr = tid >> 3, lc = (tid & 7) * 4;
    const int br = tid >> 4, bc = (tid & 15) * 4;

    float4 av  = *(const float4*)(A + (size_t)lr * 1024 + lc);
    float4 bv0 = *(const float4*)(B + (size_t)br * 512 + n0 + bc);
    float4 bv1 = *(const float4*)(B + (size_t)(br + 16) * 512 + n0 + bc);

    float c[2][4] = {};

    for (int kt = 0; kt < kend; kt += 32) {
        __syncthreads();
        As[lc + 0][lr] = av.x; As[lc + 1][lr] = av.y;
        As[lc + 2][lr] = av.z; As[lc + 3][lr] = av.w;
        *(float4*)&Bs[br][bc] = bv0;
        *(float4*)&Bs[br + 16][bc] = bv1;
        __syncthreads();
        if (kt + 32 < kend) {
            av  = *(const float4*)(A + (size_t)lr * 1024 + kt + 32 + lc);
            bv0 = *(const float4*)(B + (size_t)(kt + 32 + br) * 512 + n0 + bc);
            bv1 = *(const float4*)(B + (size_t)(kt + 48 + br) * 512 + n0 + bc);
        }
        #pragma unroll
        for (int k = 0; k < 32; ++k) {
            const float2 a = *(const float2*)&As[k][ty * 2];
            const float4 bb = *(const float4*)&Bs[k][tx * 4];
            c[0][0] = fmaf(a.x, bb.x, c[0][0]);
            c[0][1] = fmaf(a.x, bb.y, c[0][1]);
            c[0][2] = fmaf(a.x, bb.z, c[0][2]);
            c[0][3] = fmaf(a.x, bb.w, c[0][3]);
            c[1][0] = fmaf(a.y, bb.x, c[1][0]);
            c[1][1] = fmaf(a.y, bb.y, c[1][1]);
            c[1][2] = fmaf(a.y, bb.z, c[1][2]);
            c[1][3] = fmaf(a.y, bb.w, c[1][3]);
        }
    }

    #pragma unroll
    for (int i = 0; i < 2; ++i) {
        float4 o;
        o.x = c[i][0]; o.y = c[i][1]; o.z = c[i][2]; o.w = c[i][3];
        *(float4*)(out + (size_t)b * 256 * 512 +
                   (size_t)(m0 + ty * 2 + i) * 512 + n0 + tx * 4) = o;
    }
}

// ---------------------------------------------------------------------------
extern "C" void kernel_launch(void* const* d_in, const int* in_sizes, int n_in,
                              void* d_out, int out_size, void* d_ws, size_t ws_size,
                              hipStream_t stream)
{
    const float* query = (const float*)d_in[0];   // [4,256,512]
    const float* key   = (const float*)d_in[1];   // [4,1024,512]
    const float* value = (const float*)d_in[2];   // [4,1024,512]
    const int*   vlen  = (const int*)d_in[3];     // [4]
    const float* Wq    = (const float*)d_in[4];   // [512,256]
    const float* Wk    = (const float*)d_in[5];   // [512,256]
    const float* wv    = (const float*)d_in[6];   // [256]
    float* out = (float*)d_out;                   // [4,256,512]

    float*  EqT   = (float*)d_ws;                 // [256][1024]   = 262144 f
    float*  EkT   = EqT + 262144;                 // [4][256][1024]= 1048576 f
    float*  attn  = EkT + 1048576;                // [4][256][1024]= 1048576 f
    ushort* A_hi  = (ushort*)(attn + 1048576);    // [5120][512]   = 2621440 s
    ushort* A_lo  = A_hi + 2621440;
    ushort* WT_hi = A_lo + 2621440;               // [2][256][512] = 262144 s
    ushort* WT_lo = WT_hi + 262144;

    hipLaunchKernelGGL(prep_w, dim3(128), dim3(256), 0, stream,
                       Wq, Wk, WT_hi, WT_lo);
    hipLaunchKernelGGL(prep_a, dim3(1280), dim3(256), 0, stream,
                       query, key, vlen, A_hi, A_lo);
    hipLaunchKernelGGL(proj_mfma, dim3(4, 80), dim3(64), 0, stream,
                       A_hi, A_lo, WT_hi, WT_lo, vlen, EqT, EkT);
    hipLaunchKernelGGL(score_softmax_kernel, dim3(256), dim3(1024), 0, stream,
                       EqT, EkT, wv, vlen, attn);
    hipLaunchKernelGGL(pv_kernel, dim3(8, 8, 4), dim3(256), 0, stream,
                       attn, value, vlen, out);
}